// Round 4
// baseline (71.811 us; speedup 1.0000x reference)
//
#include <hip/hip_runtime.h>

#define N_B 8
#define DIM 256

constexpr float C2    = 2.8853900817779268f;   // 2*log2(e)
constexpr float LOG2E = 1.4426950408889634f;

// ---------------- proj: EQ[b][h][n] = exp2(C2*(query@Wq)), EK[b][m][h] = exp2(C2*(key@Wk)) ----
// 64x64 tile, 256 thr, 4x4/thread, k-major LDS (b128 fragment reads), double-buffered
__global__ __launch_bounds__(256) void proj_kernel(
    const float* __restrict__ query, const float* __restrict__ key,
    const float* __restrict__ Wq, const float* __restrict__ Wk,
    float* __restrict__ EQ, float* __restrict__ EK)
{
    int z = blockIdx.z;            // 0..15
    int b = z >> 1;
    bool isK = z & 1;
    const float* A = (isK ? key : query) + b * DIM * DIM;
    const float* B = isK ? Wk : Wq;

    __shared__ __align__(16) float As[2][16][68];   // [buf][k][row]
    __shared__ __align__(16) float Bs[2][16][68];   // [buf][k][col]
    __shared__ __align__(16) float T[64][68];       // transpose bounce (Q path)

    int tid = threadIdx.x;
    int tx = tid & 15, ty = tid >> 4;               // col-quad, row-quad
    int row0 = blockIdx.y * 64, col0 = blockIdx.x * 64;

    int ar = tid & 63, ak = (tid >> 6) * 4;         // A: row, k-quad
    int bk = tid >> 4, bc = (tid & 15) * 4;         // B: k, col-quad

    float acc[4][4] = {};

    {   // prologue tile 0
        float4 va = *(const float4*)&A[(row0 + ar) * DIM + ak];
        As[0][ak + 0][ar] = va.x; As[0][ak + 1][ar] = va.y;
        As[0][ak + 2][ar] = va.z; As[0][ak + 3][ar] = va.w;
        *(float4*)&Bs[0][bk][bc] = *(const float4*)&B[bk * DIM + col0 + bc];
    }
    __syncthreads();

    int buf = 0;
    for (int kb = 0; kb < 16; ++kb) {
        float4 va, vb;
        if (kb < 15) {
            va = *(const float4*)&A[(row0 + ar) * DIM + (kb + 1) * 16 + ak];
            vb = *(const float4*)&B[((kb + 1) * 16 + bk) * DIM + col0 + bc];
        }
#pragma unroll
        for (int k = 0; k < 16; ++k) {
            float4 a4 = *(const float4*)&As[buf][k][ty * 4];
            float4 b4 = *(const float4*)&Bs[buf][k][tx * 4];
            float a[4] = {a4.x, a4.y, a4.z, a4.w};
            float bb[4] = {b4.x, b4.y, b4.z, b4.w};
#pragma unroll
            for (int i = 0; i < 4; ++i)
#pragma unroll
                for (int j = 0; j < 4; ++j)
                    acc[i][j] = fmaf(a[i], bb[j], acc[i][j]);
        }
        if (kb < 15) {
            As[buf ^ 1][ak + 0][ar] = va.x; As[buf ^ 1][ak + 1][ar] = va.y;
            As[buf ^ 1][ak + 2][ar] = va.z; As[buf ^ 1][ak + 3][ar] = va.w;
            *(float4*)&Bs[buf ^ 1][bk][bc] = vb;
        }
        __syncthreads();
        buf ^= 1;
    }

#pragma unroll
    for (int i = 0; i < 4; ++i)
#pragma unroll
        for (int j = 0; j < 4; ++j)
            acc[i][j] = __builtin_amdgcn_exp2f(C2 * acc[i][j]);

    if (isK) {
        float* EKb = EK + b * DIM * DIM;           // [m][h]
#pragma unroll
        for (int i = 0; i < 4; ++i) {
            float4 v = make_float4(acc[i][0], acc[i][1], acc[i][2], acc[i][3]);
            *(float4*)&EKb[(row0 + ty * 4 + i) * DIM + col0 + tx * 4] = v;
        }
    } else {
        float* EQb = EQ + b * DIM * DIM;           // [h][n]
#pragma unroll
        for (int i = 0; i < 4; ++i)
#pragma unroll
            for (int j = 0; j < 4; ++j)
                T[ty * 4 + i][tx * 4 + j] = acc[i][j];
        __syncthreads();
        int h = tid >> 2;               // 0..63
        int n16 = (tid & 3) * 16;
        float* dst = &EQb[(col0 + h) * DIM + row0 + n16];
#pragma unroll
        for (int j4 = 0; j4 < 4; ++j4) {
            float4 v = make_float4(T[n16 + j4 * 4 + 0][h], T[n16 + j4 * 4 + 1][h],
                                   T[n16 + j4 * 4 + 2][h], T[n16 + j4 * 4 + 3][h]);
            *(float4*)(dst + j4 * 4) = v;
        }
    }
}

// ---------------- fused scores + softmax(axis=n) -> attnT[b][m][n] ----------------
// 256 thr = 4 waves; wave owns 2 m-rows x full n=256 (4 n/lane). Pair-h rcp combine.
#define MBLK 8
__global__ __launch_bounds__(256) void scores_softmax_kernel(
    const float* __restrict__ EQ, const float* __restrict__ EK,
    const float* __restrict__ Wv, float* __restrict__ attnT)
{
    int b  = blockIdx.y;
    int m0 = blockIdx.x * MBLK;
    const float* Qb = EQ + b * DIM * DIM;   // [h][n]
    const float* Kb = EK + b * DIM * DIM;   // [m][h]

    __shared__ __align__(16) float Qs[2][16 * 256];   // 32 KB double-buffered h-chunks
    __shared__ __align__(16) float Eks[MBLK][DIM];    // 8 KB, row-major (broadcast reads)
    __shared__ __align__(16) float Ws[DIM];           // 1 KB

    int tid  = threadIdx.x;
    int wave = tid >> 6, lane = tid & 63;
    int n = lane * 4;

    {   // stage EK rows (coalesced) + Wv
        int row = tid >> 5, c8 = (tid & 31) * 8;
        *(float4*)&Eks[row][c8]     = *(const float4*)&Kb[(m0 + row) * DIM + c8];
        *(float4*)&Eks[row][c8 + 4] = *(const float4*)&Kb[(m0 + row) * DIM + c8 + 4];
    }
    if (tid < 64) *(float4*)&Ws[tid * 4] = *(const float4*)&Wv[tid * 4];
    {   // chunk 0
#pragma unroll
        for (int j = 0; j < 4; ++j)
            *(float4*)&Qs[0][j * 1024 + tid * 4] = *(const float4*)&Qb[j * 1024 + tid * 4];
    }
    __syncthreads();

    // wsum = sum(Wv), wave-reduced once
    float4 w4 = *(const float4*)&Ws[lane * 4];
    float wsum = w4.x + w4.y + w4.z + w4.w;
#pragma unroll
    for (int o = 32; o; o >>= 1) wsum += __shfl_xor(wsum, o);

    float acc0[4] = {}, acc1[4] = {};
    int r0 = m0 + wave * 2, r1 = r0 + 1;

    int buf = 0;
    for (int c = 0; c < 16; ++c) {
        float4 nx[4];
        if (c < 15) {
            const float* s = Qb + (c + 1) * 4096;
#pragma unroll
            for (int j = 0; j < 4; ++j) nx[j] = *(const float4*)&s[j * 1024 + tid * 4];
        }
        const float* Qc = &Qs[buf][0];
        const float* W  = &Ws[c * 16];
        const float* E0 = &Eks[wave * 2][c * 16];
        const float* E1 = &Eks[wave * 2 + 1][c * 16];
#pragma unroll
        for (int hp = 0; hp < 8; ++hp) {
            float2 w2 = *(const float2*)&W[hp * 2];
            float2 ea = *(const float2*)&E0[hp * 2];   // ek[r0][h0], ek[r0][h1]
            float2 eb = *(const float2*)&E1[hp * 2];   // ek[r1][h0], ek[r1][h1]
            float4 q0 = *(const float4*)&Qc[(hp * 2) * 256 + n];
            float4 q1 = *(const float4*)&Qc[(hp * 2 + 1) * 256 + n];
            float q0a[4] = {q0.x, q0.y, q0.z, q0.w};
            float q1a[4] = {q1.x, q1.y, q1.z, q1.w};
#pragma unroll
            for (int j = 0; j < 4; ++j) {
                // row r0: w0/d0 + w1/d1 = (w0*d1 + w1*d0) * rcp(d0*d1)
                float d0 = fmaf(q0a[j], ea.x, 1.0f);
                float d1 = fmaf(q1a[j], ea.y, 1.0f);
                float num = fmaf(w2.y, d0, w2.x * d1);
                acc0[j] = fmaf(num, __builtin_amdgcn_rcpf(d0 * d1), acc0[j]);
                // row r1
                float e0 = fmaf(q0a[j], eb.x, 1.0f);
                float e1 = fmaf(q1a[j], eb.y, 1.0f);
                float num2 = fmaf(w2.y, e0, w2.x * e1);
                acc1[j] = fmaf(num2, __builtin_amdgcn_rcpf(e0 * e1), acc1[j]);
            }
        }
        if (c < 15) {
            float* q2 = &Qs[buf ^ 1][0];
#pragma unroll
            for (int j = 0; j < 4; ++j) *(float4*)&q2[j * 1024 + tid * 4] = nx[j];
        }
        __syncthreads();
        buf ^= 1;
    }

    // softmax over n (wave-local, no max needed: |score| <= sum|Wv| ~ 13)
    float ex0[4], ex1[4];
    float t0 = 0.0f, t1 = 0.0f;
#pragma unroll
    for (int j = 0; j < 4; ++j) {
        ex0[j] = __builtin_amdgcn_exp2f((wsum - 2.0f * acc0[j]) * LOG2E);
        ex1[j] = __builtin_amdgcn_exp2f((wsum - 2.0f * acc1[j]) * LOG2E);
        t0 += ex0[j]; t1 += ex1[j];
    }
#pragma unroll
    for (int o = 32; o; o >>= 1) { t0 += __shfl_xor(t0, o); t1 += __shfl_xor(t1, o); }
    float i0 = __builtin_amdgcn_rcpf(t0), i1 = __builtin_amdgcn_rcpf(t1);
    float4 o0 = make_float4(ex0[0] * i0, ex0[1] * i0, ex0[2] * i0, ex0[3] * i0);
    float4 o1 = make_float4(ex1[0] * i1, ex1[1] * i1, ex1[2] * i1, ex1[3] * i1);
    *(float4*)&attnT[((size_t)b * DIM + r0) * DIM + n] = o0;
    *(float4*)&attnT[((size_t)b * DIM + r1) * DIM + n] = o1;
}

// ---------------- out[b][n][d] = sum_m attnT[b][m][n] * value[b][m][d] ----
__global__ __launch_bounds__(256) void av_kernel(
    const float* __restrict__ attnT, const float* __restrict__ value,
    float* __restrict__ out)
{
    int b = blockIdx.z;
    const float* A = attnT + b * DIM * DIM;  // [m][n]
    const float* V = value + b * DIM * DIM;  // [m][d]
    float*       C = out   + b * DIM * DIM;  // [n][d]

    __shared__ __align__(16) float As[2][16][36];   // [buf][m][n]
    __shared__ __align__(16) float Bs[2][16][68];   // [buf][m][d]

    int tid = threadIdx.x;
    int tx = tid & 15, ty = tid >> 4;
    int n0 = blockIdx.y * 32, d0 = blockIdx.x * 64;

    int am = tid >> 4, an = (tid & 15) * 2;
    int bm = tid >> 4, bd = (tid & 15) * 4;

    float acc[2][4] = {};
    {
        *(float2*)&As[0][am][an] = *(const float2*)&A[am * DIM + n0 + an];
        *(float4*)&Bs[0][bm][bd] = *(const float4*)&V[bm * DIM + d0 + bd];
    }
    __syncthreads();

    int buf = 0;
    for (int mb = 0; mb < 16; ++mb) {
        float2 va; float4 vb;
        if (mb < 15) {
            va = *(const float2*)&A[((mb + 1) * 16 + am) * DIM + n0 + an];
            vb = *(const float4*)&V[((mb + 1) * 16 + bm) * DIM + d0 + bd];
        }
#pragma unroll
        for (int k = 0; k < 16; ++k) {
            float2 a2 = *(const float2*)&As[buf][k][ty * 2];
            float4 b4 = *(const float4*)&Bs[buf][k][tx * 4];
            float a[2] = {a2.x, a2.y};
            float bb[4] = {b4.x, b4.y, b4.z, b4.w};
#pragma unroll
            for (int i = 0; i < 2; ++i)
#pragma unroll
                for (int j = 0; j < 4; ++j)
                    acc[i][j] = fmaf(a[i], bb[j], acc[i][j]);
        }
        if (mb < 15) {
            *(float2*)&As[buf ^ 1][am][an] = va;
            *(float4*)&Bs[buf ^ 1][bm][bd] = vb;
        }
        __syncthreads();
        buf ^= 1;
    }
#pragma unroll
    for (int i = 0; i < 2; ++i) {
        float4 v = make_float4(acc[i][0], acc[i][1], acc[i][2], acc[i][3]);
        *(float4*)&C[((size_t)n0 + ty * 2 + i) * DIM + d0 + tx * 4] = v;
    }
}

extern "C" void kernel_launch(void* const* d_in, const int* in_sizes, int n_in,
                              void* d_out, int out_size, void* d_ws, size_t ws_size,
                              hipStream_t stream)
{
    const float* query = (const float*)d_in[0];
    const float* key   = (const float*)d_in[1];
    const float* value = (const float*)d_in[2];
    const float* Wq    = (const float*)d_in[3];
    const float* Wk    = (const float*)d_in[4];
    const float* Wv    = (const float*)d_in[5];
    float* out = (float*)d_out;

    float* EQ    = (float*)d_ws;                   // [8][h][n]
    float* EK    = EQ + N_B * DIM * DIM;           // [8][m][h]
    float* attnT = EK + N_B * DIM * DIM;           // [8][m][n]

    proj_kernel          <<<dim3(4, 4, 16), 256, 0, stream>>>(query, key, Wq, Wk, EQ, EK);
    scores_softmax_kernel<<<dim3(32, 8),    256, 0, stream>>>(EQ, EK, Wv, attnT);
    av_kernel            <<<dim3(4, 8, 8),  256, 0, stream>>>(attnT, value, out);
}

// Round 6
// 48.035 us; speedup vs baseline: 1.4950x; 1.4950x over previous
//
#include <hip/hip_runtime.h>

#define N_B 8
#define DIM 256

constexpr float C2    = 2.8853900817779268f;   // 2*log2(e)
constexpr float LOG2E = 1.4426950408889634f;

// ---------------- proj: EQ[b][h][n] = exp2(C2*(query@Wq)), EK[b][m][h] = exp2(C2*(key@Wk)) ----
// 64x64 tile, 256 thr, 4x4/thread, k-major LDS (b128 fragment reads), double-buffered
__global__ __launch_bounds__(256) void proj_kernel(
    const float* __restrict__ query, const float* __restrict__ key,
    const float* __restrict__ Wq, const float* __restrict__ Wk,
    float* __restrict__ EQ, float* __restrict__ EK)
{
    int z = blockIdx.z;            // 0..15
    int b = z >> 1;
    bool isK = z & 1;
    const float* A = (isK ? key : query) + b * DIM * DIM;
    const float* B = isK ? Wk : Wq;

    __shared__ __align__(16) float As[2][16][68];   // [buf][k][row]
    __shared__ __align__(16) float Bs[2][16][68];   // [buf][k][col]
    __shared__ __align__(16) float T[64][68];       // transpose bounce (Q path)

    int tid = threadIdx.x;
    int tx = tid & 15, ty = tid >> 4;               // col-quad, row-quad
    int row0 = blockIdx.y * 64, col0 = blockIdx.x * 64;

    int ar = tid & 63, ak = (tid >> 6) * 4;         // A: row, k-quad
    int bk = tid >> 4, bc = (tid & 15) * 4;         // B: k, col-quad

    float acc[4][4] = {};

    {   // prologue tile 0
        float4 va = *(const float4*)&A[(row0 + ar) * DIM + ak];
        As[0][ak + 0][ar] = va.x; As[0][ak + 1][ar] = va.y;
        As[0][ak + 2][ar] = va.z; As[0][ak + 3][ar] = va.w;
        *(float4*)&Bs[0][bk][bc] = *(const float4*)&B[bk * DIM + col0 + bc];
    }
    __syncthreads();

    int buf = 0;
    for (int kb = 0; kb < 16; ++kb) {
        float4 va, vb;
        if (kb < 15) {
            va = *(const float4*)&A[(row0 + ar) * DIM + (kb + 1) * 16 + ak];
            vb = *(const float4*)&B[((kb + 1) * 16 + bk) * DIM + col0 + bc];
        }
#pragma unroll
        for (int k = 0; k < 16; ++k) {
            float4 a4 = *(const float4*)&As[buf][k][ty * 4];
            float4 b4 = *(const float4*)&Bs[buf][k][tx * 4];
            float a[4] = {a4.x, a4.y, a4.z, a4.w};
            float bb[4] = {b4.x, b4.y, b4.z, b4.w};
#pragma unroll
            for (int i = 0; i < 4; ++i)
#pragma unroll
                for (int j = 0; j < 4; ++j)
                    acc[i][j] = fmaf(a[i], bb[j], acc[i][j]);
        }
        if (kb < 15) {
            As[buf ^ 1][ak + 0][ar] = va.x; As[buf ^ 1][ak + 1][ar] = va.y;
            As[buf ^ 1][ak + 2][ar] = va.z; As[buf ^ 1][ak + 3][ar] = va.w;
            *(float4*)&Bs[buf ^ 1][bk][bc] = vb;
        }
        __syncthreads();
        buf ^= 1;
    }

#pragma unroll
    for (int i = 0; i < 4; ++i)
#pragma unroll
        for (int j = 0; j < 4; ++j)
            acc[i][j] = __builtin_amdgcn_exp2f(C2 * acc[i][j]);

    if (isK) {
        float* EKb = EK + b * DIM * DIM;           // [m][h]
#pragma unroll
        for (int i = 0; i < 4; ++i) {
            float4 v = make_float4(acc[i][0], acc[i][1], acc[i][2], acc[i][3]);
            *(float4*)&EKb[(row0 + ty * 4 + i) * DIM + col0 + tx * 4] = v;
        }
    } else {
        float* EQb = EQ + b * DIM * DIM;           // [h][n]
#pragma unroll
        for (int i = 0; i < 4; ++i)
#pragma unroll
            for (int j = 0; j < 4; ++j)
                T[ty * 4 + i][tx * 4 + j] = acc[i][j];
        __syncthreads();
        int h = tid >> 2;               // 0..63
        int n16 = (tid & 3) * 16;
        float* dst = &EQb[(col0 + h) * DIM + row0 + n16];
#pragma unroll
        for (int j4 = 0; j4 < 4; ++j4) {
            float4 v = make_float4(T[n16 + j4 * 4 + 0][h], T[n16 + j4 * 4 + 1][h],
                                   T[n16 + j4 * 4 + 2][h], T[n16 + j4 * 4 + 3][h]);
            *(float4*)(dst + j4 * 4) = v;
        }
    }
}

// ---------------- fused scores + softmax(axis=n) -> attnT[b][m][n] ----------------
// 512 thr = 8 waves = (2 row-pairs) x (2 h-halves) x (2 n-halves); 512 blocks -> 4 waves/SIMD.
// Per-chunk uniforms (Wv, EK) hoisted to registers; inner loop: 2 LDS b64 + 24 VALU + 4 rcp.
#define CH 16
__global__ __launch_bounds__(512, 4) void scores_softmax_kernel(
    const float* __restrict__ EQ, const float* __restrict__ EK,
    const float* __restrict__ Wv, float* __restrict__ attnT)
{
    int b  = blockIdx.y;
    int m0 = blockIdx.x * 4;
    const float* Qb = EQ + b * DIM * DIM;   // [h][n]
    const float* Kb = EK + b * DIM * DIM;   // [m][h]

    __shared__ __align__(16) float Qs[2][CH * 256];   // 32 KB dbuf
    __shared__ __align__(16) float Eks[4][DIM];       // 4 KB
    __shared__ __align__(16) float Ws[DIM];           // 1 KB
    __shared__ __align__(16) float part[2][2][64][4]; // 4 KB [rp][nh][lane][4]
    __shared__ float red[2][2][2];                    // [rp][nh][row]

    int tid  = threadIdx.x;
    int w    = tid >> 6, lane = tid & 63;
    int rp = w >> 2, hs = (w >> 1) & 1, nh = w & 1;
    int n = nh * 128 + lane * 2;

    {   // stage EK rows + Wv + chunk 0
        int row = tid >> 7, c2 = (tid & 127) * 2;
        *(float2*)&Eks[row][c2] = *(const float2*)&Kb[(m0 + row) * DIM + c2];
    }
    if (tid < 64) *(float4*)&Ws[tid * 4] = *(const float4*)&Wv[tid * 4];
#pragma unroll
    for (int j = 0; j < 2; ++j)
        *(float4*)&Qs[0][j * 2048 + tid * 4] = *(const float4*)&Qb[j * 2048 + tid * 4];
    __syncthreads();

    float wsum;
    {
        float4 w4 = *(const float4*)&Ws[lane * 4];
        wsum = w4.x + w4.y + w4.z + w4.w;
#pragma unroll
        for (int o = 32; o; o >>= 1) wsum += __shfl_xor(wsum, o);
    }

    float acc[2][2] = {};   // [row][n-sub]
    int buf = 0;

    for (int c = 0; c < 16; ++c) {
        float4 nx0, nx1;
        if (c < 15) {
            const float* s = Qb + (c + 1) * CH * 256;
            nx0 = *(const float4*)&s[tid * 4];
            nx1 = *(const float4*)&s[2048 + tid * 4];
        }
        // chunk-uniform registers: 8 h owned by this wave's h-half
        float wreg[8], e0reg[8], e1reg[8];
#pragma unroll
        for (int i = 0; i < 2; ++i) {
            *(float4*)&wreg[i * 4]  = *(const float4*)&Ws[c * CH + hs * 8 + i * 4];
            *(float4*)&e0reg[i * 4] = *(const float4*)&Eks[rp * 2][c * CH + hs * 8 + i * 4];
            *(float4*)&e1reg[i * 4] = *(const float4*)&Eks[rp * 2 + 1][c * CH + hs * 8 + i * 4];
        }
        const float* Qc = &Qs[buf][hs * 8 * 256];
#pragma unroll
        for (int hp = 0; hp < 4; ++hp) {
            float2 q0 = *(const float2*)&Qc[(hp * 2) * 256 + n];
            float2 q1 = *(const float2*)&Qc[(hp * 2 + 1) * 256 + n];
            float w0 = wreg[hp * 2], w1 = wreg[hp * 2 + 1];
            // row 0: w0/d0 + w1/d1 = (w0*d1 + w1*d0)*rcp(d0*d1)
            {
                float d0 = fmaf(q0.x, e0reg[hp * 2], 1.0f);
                float d1 = fmaf(q1.x, e0reg[hp * 2 + 1], 1.0f);
                float num = fmaf(w0, d1, w1 * d0);
                acc[0][0] = fmaf(num, __builtin_amdgcn_rcpf(d0 * d1), acc[0][0]);
                d0 = fmaf(q0.y, e0reg[hp * 2], 1.0f);
                d1 = fmaf(q1.y, e0reg[hp * 2 + 1], 1.0f);
                num = fmaf(w0, d1, w1 * d0);
                acc[0][1] = fmaf(num, __builtin_amdgcn_rcpf(d0 * d1), acc[0][1]);
            }
            {
                float d0 = fmaf(q0.x, e1reg[hp * 2], 1.0f);
                float d1 = fmaf(q1.x, e1reg[hp * 2 + 1], 1.0f);
                float num = fmaf(w0, d1, w1 * d0);
                acc[1][0] = fmaf(num, __builtin_amdgcn_rcpf(d0 * d1), acc[1][0]);
                d0 = fmaf(q0.y, e1reg[hp * 2], 1.0f);
                d1 = fmaf(q1.y, e1reg[hp * 2 + 1], 1.0f);
                num = fmaf(w0, d1, w1 * d0);
                acc[1][1] = fmaf(num, __builtin_amdgcn_rcpf(d0 * d1), acc[1][1]);
            }
        }
        if (c < 15) {
            *(float4*)&Qs[buf ^ 1][tid * 4] = nx0;
            *(float4*)&Qs[buf ^ 1][2048 + tid * 4] = nx1;
        }
        __syncthreads();
        buf ^= 1;
    }

    // combine h-halves: hs==1 writes partials, hs==0 accumulates
    if (hs == 1) {
        float4 v = make_float4(acc[0][0], acc[0][1], acc[1][0], acc[1][1]);
        *(float4*)&part[rp][nh][lane][0] = v;
    }
    __syncthreads();

    float e00, e01, e10, e11, t0, t1;
    if (hs == 0) {
        float4 v = *(const float4*)&part[rp][nh][lane][0];
        acc[0][0] += v.x; acc[0][1] += v.y; acc[1][0] += v.z; acc[1][1] += v.w;
        // softmax over n (no max subtraction: |score| <= sum|Wv| ~ 13)
        e00 = __builtin_amdgcn_exp2f((wsum - 2.0f * acc[0][0]) * LOG2E);
        e01 = __builtin_amdgcn_exp2f((wsum - 2.0f * acc[0][1]) * LOG2E);
        e10 = __builtin_amdgcn_exp2f((wsum - 2.0f * acc[1][0]) * LOG2E);
        e11 = __builtin_amdgcn_exp2f((wsum - 2.0f * acc[1][1]) * LOG2E);
        t0 = e00 + e01; t1 = e10 + e11;
#pragma unroll
        for (int o = 32; o; o >>= 1) { t0 += __shfl_xor(t0, o); t1 += __shfl_xor(t1, o); }
        if (lane == 0) { red[rp][nh][0] = t0; red[rp][nh][1] = t1; }
    }
    __syncthreads();
    if (hs == 0) {
        float tot0 = red[rp][0][0] + red[rp][1][0];
        float tot1 = red[rp][0][1] + red[rp][1][1];
        float i0 = __builtin_amdgcn_rcpf(tot0);
        float i1 = __builtin_amdgcn_rcpf(tot1);
        float2 o0 = {e00 * i0, e01 * i0};
        float2 o1 = {e10 * i1, e11 * i1};
        *(float2*)&attnT[((size_t)b * DIM + m0 + rp * 2) * DIM + n] = o0;
        *(float2*)&attnT[((size_t)b * DIM + m0 + rp * 2 + 1) * DIM + n] = o1;
    }
}

// ---------------- out[b][n][d] = sum_m attnT[b][m][n] * value[b][m][d] ----
__global__ __launch_bounds__(256) void av_kernel(
    const float* __restrict__ attnT, const float* __restrict__ value,
    float* __restrict__ out)
{
    int b = blockIdx.z;
    const float* A = attnT + b * DIM * DIM;  // [m][n]
    const float* V = value + b * DIM * DIM;  // [m][d]
    float*       C = out   + b * DIM * DIM;  // [n][d]

    __shared__ __align__(16) float As[2][16][36];   // [buf][m][n]
    __shared__ __align__(16) float Bs[2][16][68];   // [buf][m][d]

    int tid = threadIdx.x;
    int tx = tid & 15, ty = tid >> 4;
    int n0 = blockIdx.y * 32, d0 = blockIdx.x * 64;

    int am = tid >> 4, an = (tid & 15) * 2;
    int bm = tid >> 4, bd = (tid & 15) * 4;

    float acc[2][4] = {};
    {
        *(float2*)&As[0][am][an] = *(const float2*)&A[am * DIM + n0 + an];
        *(float4*)&Bs[0][bm][bd] = *(const float4*)&V[bm * DIM + d0 + bd];
    }
    __syncthreads();

    int buf = 0;
    for (int mb = 0; mb < 16; ++mb) {
        float2 va; float4 vb;
        if (mb < 15) {
            va = *(const float2*)&A[((mb + 1) * 16 + am) * DIM + n0 + an];
            vb = *(const float4*)&V[((mb + 1) * 16 + bm) * DIM + d0 + bd];
        }
#pragma unroll
        for (int k = 0; k < 16; ++k) {
            float2 a2 = *(const float2*)&As[buf][k][ty * 2];
            float4 b4 = *(const float4*)&Bs[buf][k][tx * 4];
            float a[2] = {a2.x, a2.y};
            float bb[4] = {b4.x, b4.y, b4.z, b4.w};
#pragma unroll
            for (int i = 0; i < 2; ++i)
#pragma unroll
                for (int j = 0; j < 4; ++j)
                    acc[i][j] = fmaf(a[i], bb[j], acc[i][j]);
        }
        if (mb < 15) {
            *(float2*)&As[buf ^ 1][am][an] = va;
            *(float4*)&Bs[buf ^ 1][bm][bd] = vb;
        }
        __syncthreads();
        buf ^= 1;
    }
#pragma unroll
    for (int i = 0; i < 2; ++i) {
        float4 v = make_float4(acc[i][0], acc[i][1], acc[i][2], acc[i][3]);
        *(float4*)&C[((size_t)n0 + ty * 2 + i) * DIM + d0 + tx * 4] = v;
    }
}

extern "C" void kernel_launch(void* const* d_in, const int* in_sizes, int n_in,
                              void* d_out, int out_size, void* d_ws, size_t ws_size,
                              hipStream_t stream)
{
    const float* query = (const float*)d_in[0];
    const float* key   = (const float*)d_in[1];
    const float* value = (const float*)d_in[2];
    const float* Wq    = (const float*)d_in[3];
    const float* Wk    = (const float*)d_in[4];
    const float* Wv    = (const float*)d_in[5];
    float* out = (float*)d_out;

    float* EQ    = (float*)d_ws;                   // [8][h][n]
    float* EK    = EQ + N_B * DIM * DIM;           // [8][m][h]
    float* attnT = EK + N_B * DIM * DIM;           // [8][m][n]

    proj_kernel          <<<dim3(4, 4, 16), 256, 0, stream>>>(query, key, Wq, Wk, EQ, EK);
    scores_softmax_kernel<<<dim3(64, 8),    512, 0, stream>>>(EQ, EK, Wv, attnT);
    av_kernel            <<<dim3(4, 8, 8),  256, 0, stream>>>(attnT, value, out);
}

// Round 7
// 46.421 us; speedup vs baseline: 1.5470x; 1.0348x over previous
//
#include <hip/hip_runtime.h>

#define N_B 8
#define DIM 256

constexpr float C2    = 2.8853900817779268f;   // 2*log2(e)
constexpr float LOG2E = 1.4426950408889634f;

// ---------------- proj: EQ[b][h][n] = exp2(C2*(query@Wq)), EK[b][m][h] = exp2(C2*(key@Wk)) ----
// 64x64 tile, 256 thr, 4x4/thread, k-major LDS (b128 fragment reads), double-buffered
__global__ __launch_bounds__(256) void proj_kernel(
    const float* __restrict__ query, const float* __restrict__ key,
    const float* __restrict__ Wq, const float* __restrict__ Wk,
    float* __restrict__ EQ, float* __restrict__ EK)
{
    int z = blockIdx.z;            // 0..15
    int b = z >> 1;
    bool isK = z & 1;
    const float* A = (isK ? key : query) + b * DIM * DIM;
    const float* B = isK ? Wk : Wq;

    __shared__ __align__(16) float As[2][16][68];   // [buf][k][row]
    __shared__ __align__(16) float Bs[2][16][68];   // [buf][k][col]
    __shared__ __align__(16) float T[64][68];       // transpose bounce (Q path)

    int tid = threadIdx.x;
    int tx = tid & 15, ty = tid >> 4;               // col-quad, row-quad
    int row0 = blockIdx.y * 64, col0 = blockIdx.x * 64;

    int ar = tid & 63, ak = (tid >> 6) * 4;         // A: row, k-quad
    int bk = tid >> 4, bc = (tid & 15) * 4;         // B: k, col-quad

    float acc[4][4] = {};

    {   // prologue tile 0
        float4 va = *(const float4*)&A[(row0 + ar) * DIM + ak];
        As[0][ak + 0][ar] = va.x; As[0][ak + 1][ar] = va.y;
        As[0][ak + 2][ar] = va.z; As[0][ak + 3][ar] = va.w;
        *(float4*)&Bs[0][bk][bc] = *(const float4*)&B[bk * DIM + col0 + bc];
    }
    __syncthreads();

    int buf = 0;
    for (int kb = 0; kb < 16; ++kb) {
        float4 va, vb;
        if (kb < 15) {
            va = *(const float4*)&A[(row0 + ar) * DIM + (kb + 1) * 16 + ak];
            vb = *(const float4*)&B[((kb + 1) * 16 + bk) * DIM + col0 + bc];
        }
#pragma unroll
        for (int k = 0; k < 16; ++k) {
            float4 a4 = *(const float4*)&As[buf][k][ty * 4];
            float4 b4 = *(const float4*)&Bs[buf][k][tx * 4];
            float a[4] = {a4.x, a4.y, a4.z, a4.w};
            float bb[4] = {b4.x, b4.y, b4.z, b4.w};
#pragma unroll
            for (int i = 0; i < 4; ++i)
#pragma unroll
                for (int j = 0; j < 4; ++j)
                    acc[i][j] = fmaf(a[i], bb[j], acc[i][j]);
        }
        if (kb < 15) {
            As[buf ^ 1][ak + 0][ar] = va.x; As[buf ^ 1][ak + 1][ar] = va.y;
            As[buf ^ 1][ak + 2][ar] = va.z; As[buf ^ 1][ak + 3][ar] = va.w;
            *(float4*)&Bs[buf ^ 1][bk][bc] = vb;
        }
        __syncthreads();
        buf ^= 1;
    }

#pragma unroll
    for (int i = 0; i < 4; ++i)
#pragma unroll
        for (int j = 0; j < 4; ++j)
            acc[i][j] = __builtin_amdgcn_exp2f(C2 * acc[i][j]);

    if (isK) {
        float* EKb = EK + b * DIM * DIM;           // [m][h]
#pragma unroll
        for (int i = 0; i < 4; ++i) {
            float4 v = make_float4(acc[i][0], acc[i][1], acc[i][2], acc[i][3]);
            *(float4*)&EKb[(row0 + ty * 4 + i) * DIM + col0 + tx * 4] = v;
        }
    } else {
        float* EQb = EQ + b * DIM * DIM;           // [h][n]
#pragma unroll
        for (int i = 0; i < 4; ++i)
#pragma unroll
            for (int j = 0; j < 4; ++j)
                T[ty * 4 + i][tx * 4 + j] = acc[i][j];
        __syncthreads();
        int h = tid >> 2;               // 0..63
        int n16 = (tid & 3) * 16;
        float* dst = &EQb[(col0 + h) * DIM + row0 + n16];
#pragma unroll
        for (int j4 = 0; j4 < 4; ++j4) {
            float4 v = make_float4(T[n16 + j4 * 4 + 0][h], T[n16 + j4 * 4 + 1][h],
                                   T[n16 + j4 * 4 + 2][h], T[n16 + j4 * 4 + 3][h]);
            *(float4*)(dst + j4 * 4) = v;
        }
    }
}

// ---------------- fused scores + softmax(axis=n) -> attnT[b][m][n] ----------------
// 512 thr = 8 waves = (2 m-groups of 4 rows) x (4 h-splits). Lane: 4 m x 4 n.
// grid 256 blocks (1/CU). LDS:VALU balanced (~11 b128/wave/chunk vs 192 FMA + 32 rcp).
#define CH 16
__global__ __launch_bounds__(512, 2) void scores_softmax_kernel(
    const float* __restrict__ EQ, const float* __restrict__ EK,
    const float* __restrict__ Wv, float* __restrict__ attnT)
{
    int b  = blockIdx.y;
    int M0 = blockIdx.x * 8;
    const float* Qb = EQ + b * DIM * DIM;   // [h][n]
    const float* Kb = EK + b * DIM * DIM;   // [m][h]

    __shared__ __align__(16) float Qs[2][CH * 256];    // 32 KB dbuf h-chunks
    __shared__ __align__(16) float Eks[8][DIM];        // 8 KB [m][h]
    __shared__ __align__(16) float Ws[DIM];            // 1 KB
    __shared__ __align__(16) float part[3][2][64][16]; // 24 KB h-split exchange

    int tid  = threadIdx.x;
    int w = tid >> 6, lane = tid & 63;
    int mg = w & 1, hs = w >> 1;      // m-group 0..1, h-split 0..3
    int n0 = lane * 4;

    {   // stage Eks: 8 m-rows x 256 h (coalesced b128 per row)
        int m = tid >> 6, h4 = (tid & 63) * 4;
        *(float4*)&Eks[m][h4] = *(const float4*)&Kb[(M0 + m) * DIM + h4];
    }
    if (tid < 64) *(float4*)&Ws[tid * 4] = *(const float4*)&Wv[tid * 4];
    *(float4*)&Qs[0][tid * 4]        = *(const float4*)&Qb[tid * 4];
    *(float4*)&Qs[0][2048 + tid * 4] = *(const float4*)&Qb[2048 + tid * 4];
    __syncthreads();

    float wsum;
    {
        float4 w4 = *(const float4*)&Ws[lane * 4];
        wsum = w4.x + w4.y + w4.z + w4.w;
#pragma unroll
        for (int o = 32; o; o >>= 1) wsum += __shfl_xor(wsum, o);
    }

    float acc[4][4] = {};   // [m-row][n]
    int buf = 0;

    for (int c = 0; c < 16; ++c) {
        float4 nx0, nx1;
        if (c < 15) {
            const float* s = Qb + (c + 1) * (CH * 256);
            nx0 = *(const float4*)&s[tid * 4];
            nx1 = *(const float4*)&s[2048 + tid * 4];
        }
        // wave-uniform chunk values (broadcast LDS reads)
        float4 wv4 = *(const float4*)&Ws[c * CH + hs * 4];
        float wva[4] = {wv4.x, wv4.y, wv4.z, wv4.w};
        float eka[4][4];
#pragma unroll
        for (int i = 0; i < 4; ++i) {
            float4 e4 = *(const float4*)&Eks[mg * 4 + i][c * CH + hs * 4];
            eka[i][0] = e4.x; eka[i][1] = e4.y; eka[i][2] = e4.z; eka[i][3] = e4.w;
        }
        const float* Qc = &Qs[buf][(hs * 4) * 256];
#pragma unroll
        for (int hh = 0; hh < 2; ++hh) {
            float4 q0 = *(const float4*)&Qc[(hh * 2) * 256 + n0];
            float4 q1 = *(const float4*)&Qc[(hh * 2 + 1) * 256 + n0];
            float q0a[4] = {q0.x, q0.y, q0.z, q0.w};
            float q1a[4] = {q1.x, q1.y, q1.z, q1.w};
            float w0 = wva[hh * 2], w1 = wva[hh * 2 + 1];
#pragma unroll
            for (int i = 0; i < 4; ++i) {
                float e0 = eka[i][hh * 2], e1 = eka[i][hh * 2 + 1];
#pragma unroll
                for (int j = 0; j < 4; ++j) {
                    float d0 = fmaf(q0a[j], e0, 1.0f);
                    float d1 = fmaf(q1a[j], e1, 1.0f);
                    float num = fmaf(w0, d1, w1 * d0);
                    acc[i][j] = fmaf(num, __builtin_amdgcn_rcpf(d0 * d1), acc[i][j]);
                }
            }
        }
        if (c < 15) {
            *(float4*)&Qs[buf ^ 1][tid * 4] = nx0;
            *(float4*)&Qs[buf ^ 1][2048 + tid * 4] = nx1;
        }
        __syncthreads();
        buf ^= 1;
    }

    // combine h-splits: hs 1..3 deposit partials, hs 0 reduces + softmax + write
    if (hs) {
#pragma unroll
        for (int i = 0; i < 4; ++i) {
            float4 v = make_float4(acc[i][0], acc[i][1], acc[i][2], acc[i][3]);
            *(float4*)&part[hs - 1][mg][lane][i * 4] = v;
        }
    }
    __syncthreads();
    if (hs == 0) {
#pragma unroll
        for (int p = 0; p < 3; ++p)
#pragma unroll
            for (int i = 0; i < 4; ++i) {
                float4 v = *(const float4*)&part[p][mg][lane][i * 4];
                acc[i][0] += v.x; acc[i][1] += v.y; acc[i][2] += v.z; acc[i][3] += v.w;
            }
        // softmax over n (no max subtraction: |score| <= sum|Wv| ~ 13)
        float e[4][4], t[4];
#pragma unroll
        for (int i = 0; i < 4; ++i) {
            t[i] = 0.0f;
#pragma unroll
            for (int j = 0; j < 4; ++j) {
                e[i][j] = __builtin_amdgcn_exp2f((wsum - 2.0f * acc[i][j]) * LOG2E);
                t[i] += e[i][j];
            }
        }
#pragma unroll
        for (int o = 32; o; o >>= 1)
#pragma unroll
            for (int i = 0; i < 4; ++i) t[i] += __shfl_xor(t[i], o);
#pragma unroll
        for (int i = 0; i < 4; ++i) {
            float r = __builtin_amdgcn_rcpf(t[i]);
            float4 outv = make_float4(e[i][0] * r, e[i][1] * r, e[i][2] * r, e[i][3] * r);
            *(float4*)&attnT[((size_t)b * DIM + M0 + mg * 4 + i) * DIM + n0] = outv;
        }
    }
}

// ---------------- out[b][n][d] = sum_m attnT[b][m][n] * value[b][m][d] ----
__global__ __launch_bounds__(256) void av_kernel(
    const float* __restrict__ attnT, const float* __restrict__ value,
    float* __restrict__ out)
{
    int b = blockIdx.z;
    const float* A = attnT + b * DIM * DIM;  // [m][n]
    const float* V = value + b * DIM * DIM;  // [m][d]
    float*       C = out   + b * DIM * DIM;  // [n][d]

    __shared__ __align__(16) float As[2][16][36];   // [buf][m][n]
    __shared__ __align__(16) float Bs[2][16][68];   // [buf][m][d]

    int tid = threadIdx.x;
    int tx = tid & 15, ty = tid >> 4;
    int n0 = blockIdx.y * 32, d0 = blockIdx.x * 64;

    int am = tid >> 4, an = (tid & 15) * 2;
    int bm = tid >> 4, bd = (tid & 15) * 4;

    float acc[2][4] = {};
    {
        *(float2*)&As[0][am][an] = *(const float2*)&A[am * DIM + n0 + an];
        *(float4*)&Bs[0][bm][bd] = *(const float4*)&V[bm * DIM + d0 + bd];
    }
    __syncthreads();

    int buf = 0;
    for (int mb = 0; mb < 16; ++mb) {
        float2 va; float4 vb;
        if (mb < 15) {
            va = *(const float2*)&A[((mb + 1) * 16 + am) * DIM + n0 + an];
            vb = *(const float4*)&V[((mb + 1) * 16 + bm) * DIM + d0 + bd];
        }
#pragma unroll
        for (int k = 0; k < 16; ++k) {
            float2 a2 = *(const float2*)&As[buf][k][ty * 2];
            float4 b4 = *(const float4*)&Bs[buf][k][tx * 4];
            float a[2] = {a2.x, a2.y};
            float bb[4] = {b4.x, b4.y, b4.z, b4.w};
#pragma unroll
            for (int i = 0; i < 2; ++i)
#pragma unroll
                for (int j = 0; j < 4; ++j)
                    acc[i][j] = fmaf(a[i], bb[j], acc[i][j]);
        }
        if (mb < 15) {
            *(float2*)&As[buf ^ 1][am][an] = va;
            *(float4*)&Bs[buf ^ 1][bm][bd] = vb;
        }
        __syncthreads();
        buf ^= 1;
    }
#pragma unroll
    for (int i = 0; i < 2; ++i) {
        float4 v = make_float4(acc[i][0], acc[i][1], acc[i][2], acc[i][3]);
        *(float4*)&C[((size_t)n0 + ty * 2 + i) * DIM + d0 + tx * 4] = v;
    }
}

extern "C" void kernel_launch(void* const* d_in, const int* in_sizes, int n_in,
                              void* d_out, int out_size, void* d_ws, size_t ws_size,
                              hipStream_t stream)
{
    const float* query = (const float*)d_in[0];
    const float* key   = (const float*)d_in[1];
    const float* value = (const float*)d_in[2];
    const float* Wq    = (const float*)d_in[3];
    const float* Wk    = (const float*)d_in[4];
    const float* Wv    = (const float*)d_in[5];
    float* out = (float*)d_out;

    float* EQ    = (float*)d_ws;                   // [8][h][n]
    float* EK    = EQ + N_B * DIM * DIM;           // [8][m][h]
    float* attnT = EK + N_B * DIM * DIM;           // [8][m][n]

    proj_kernel          <<<dim3(4, 4, 16), 256, 0, stream>>>(query, key, Wq, Wk, EQ, EK);
    scores_softmax_kernel<<<dim3(32, 8),    512, 0, stream>>>(EQ, EK, Wv, attnT);
    av_kernel            <<<dim3(4, 8, 8),  256, 0, stream>>>(attnT, value, out);
}

// Round 8
// 44.853 us; speedup vs baseline: 1.6010x; 1.0350x over previous
//
#include <hip/hip_runtime.h>

#define N_B 8
#define DIM 256

constexpr float C2    = 2.8853900817779268f;   // 2*log2(e)
constexpr float LOG2E = 1.4426950408889634f;

typedef __attribute__((ext_vector_type(8))) short short8;
typedef __attribute__((ext_vector_type(4))) float f32x4;
typedef unsigned short ushort_t;

// pack two floats' top-16 bits as 2 bf16 (truncation; residual captured by lo)
__device__ __forceinline__ unsigned hi2(float a, float b) {
    return (__float_as_uint(a) >> 16) | (__float_as_uint(b) & 0xFFFF0000u);
}
__device__ __forceinline__ float trunc_res(float a) {
    return a - __uint_as_float(__float_as_uint(a) & 0xFFFF0000u);
}

// ---------------- prep: transpose + bf16 hi/lo split ----------------
// Wq,Wk [k][c] -> WT[c][k]; V[m][d] -> VT[d][m]
__global__ __launch_bounds__(256) void prep_kernel(
    const float* __restrict__ Wq, const float* __restrict__ Wk,
    const float* __restrict__ V,
    ushort_t* __restrict__ WqT_hi, ushort_t* __restrict__ WqT_lo,
    ushort_t* __restrict__ WkT_hi, ushort_t* __restrict__ WkT_lo,
    ushort_t* __restrict__ VT_hi,  ushort_t* __restrict__ VT_lo)
{
    __shared__ __align__(16) float T[64][68];
    int id = blockIdx.x;
    const float* src; ushort_t *dhi, *dlo; int t;
    if (id < 16)      { src = Wq; dhi = WqT_hi; dlo = WqT_lo; t = id; }
    else if (id < 32) { src = Wk; dhi = WkT_hi; dlo = WkT_lo; t = id - 16; }
    else {
        int v = id - 32; int b = v >> 4; t = v & 15;
        src = V + b * DIM * DIM; dhi = VT_hi + b * DIM * DIM; dlo = VT_lo + b * DIM * DIM;
    }
    int R0 = (t >> 2) * 64, C0 = (t & 3) * 64;
    int tt = threadIdx.x;
    int r = tt >> 2, q = tt & 3;
#pragma unroll
    for (int i = 0; i < 4; ++i)
        *(float4*)&T[r][q * 16 + i * 4] = *(const float4*)&src[(size_t)(R0 + r) * DIM + C0 + q * 16 + i * 4];
    __syncthreads();
    // thread emits out[C0+r][R0 + q*16 .. +15]  (r reused as local col)
    float f[16];
#pragma unroll
    for (int j = 0; j < 16; ++j) f[j] = T[q * 16 + j][r];
    unsigned h[8], l[8];
#pragma unroll
    for (int j = 0; j < 8; ++j) {
        h[j] = hi2(f[2 * j], f[2 * j + 1]);
        l[j] = hi2(trunc_res(f[2 * j]), trunc_res(f[2 * j + 1]));
    }
    size_t base = (size_t)(C0 + r) * DIM + R0 + q * 16;
    *(uint4*)&dhi[base]     = make_uint4(h[0], h[1], h[2], h[3]);
    *(uint4*)&dhi[base + 8] = make_uint4(h[4], h[5], h[6], h[7]);
    *(uint4*)&dlo[base]     = make_uint4(l[0], l[1], l[2], l[3]);
    *(uint4*)&dlo[base + 8] = make_uint4(l[4], l[5], l[6], l[7]);
}

// ---------------- proj (MFMA): EQ[b][h][n]=exp2(C2*(A@W)) transposed, EK[b][m][h] ----------------
// 64x64 tile, 4 waves (2x2 of 32x32), bf16 hi/lo split, 4 MFMAs/product pair.
__global__ __launch_bounds__(256) void proj_mfma(
    const float* __restrict__ query, const float* __restrict__ key,
    const ushort_t* __restrict__ WqT_hi, const ushort_t* __restrict__ WqT_lo,
    const ushort_t* __restrict__ WkT_hi, const ushort_t* __restrict__ WkT_lo,
    float* __restrict__ EQ, float* __restrict__ EK)
{
    __shared__ __align__(16) ushort_t Ah[64 * 64], Al[64 * 64], Bh[64 * 64], Bl[64 * 64];
    __shared__ __align__(16) float T[64][68];

    int y = blockIdx.y;
    int b = y >> 1; bool isK = y & 1;
    const float* A = (isK ? key : query) + b * DIM * DIM;
    const ushort_t* BThi = isK ? WkT_hi : WqT_hi;
    const ushort_t* BTlo = isK ? WkT_lo : WqT_lo;

    int x = blockIdx.x;
    int R0 = (x >> 2) * 64, C0 = (x & 3) * 64;

    int tid = threadIdx.x;
    int w = tid >> 6, lane = tid & 63;
    int wr = w >> 1, wc = w & 1;
    int l15 = lane & 15, l4 = lane >> 4;

    int sr = tid >> 2, skq = (tid & 3) * 16;    // staging: row/col 0..63, k-quarter

    f32x4 acc[2][2] = {};
    float4 areg0, areg1, areg2, areg3;
    uint4 bh0, bh1, bl0, bl1;

    // prologue loads (stage 0)
    {
        const float* ap = &A[(size_t)(R0 + sr) * DIM + skq];
        areg0 = *(const float4*)&ap[0];  areg1 = *(const float4*)&ap[4];
        areg2 = *(const float4*)&ap[8];  areg3 = *(const float4*)&ap[12];
        size_t bb = (size_t)(C0 + sr) * DIM + skq;
        bh0 = *(const uint4*)&BThi[bb]; bh1 = *(const uint4*)&BThi[bb + 8];
        bl0 = *(const uint4*)&BTlo[bb]; bl1 = *(const uint4*)&BTlo[bb + 8];
    }

    for (int ks = 0; ks < 4; ++ks) {
        // write staged regs -> LDS (XOR swizzle, 16B granules)
        {
            int i0 = (sr * 64 + skq)     ^ ((sr & 7) << 3);
            int i1 = (sr * 64 + skq + 8) ^ ((sr & 7) << 3);
            uint4 hv0 = make_uint4(hi2(areg0.x, areg0.y), hi2(areg0.z, areg0.w),
                                   hi2(areg1.x, areg1.y), hi2(areg1.z, areg1.w));
            uint4 hv1 = make_uint4(hi2(areg2.x, areg2.y), hi2(areg2.z, areg2.w),
                                   hi2(areg3.x, areg3.y), hi2(areg3.z, areg3.w));
            uint4 lv0 = make_uint4(hi2(trunc_res(areg0.x), trunc_res(areg0.y)),
                                   hi2(trunc_res(areg0.z), trunc_res(areg0.w)),
                                   hi2(trunc_res(areg1.x), trunc_res(areg1.y)),
                                   hi2(trunc_res(areg1.z), trunc_res(areg1.w)));
            uint4 lv1 = make_uint4(hi2(trunc_res(areg2.x), trunc_res(areg2.y)),
                                   hi2(trunc_res(areg2.z), trunc_res(areg2.w)),
                                   hi2(trunc_res(areg3.x), trunc_res(areg3.y)),
                                   hi2(trunc_res(areg3.z), trunc_res(areg3.w)));
            *(uint4*)&Ah[i0] = hv0; *(uint4*)&Ah[i1] = hv1;
            *(uint4*)&Al[i0] = lv0; *(uint4*)&Al[i1] = lv1;
            *(uint4*)&Bh[i0] = bh0; *(uint4*)&Bh[i1] = bh1;
            *(uint4*)&Bl[i0] = bl0; *(uint4*)&Bl[i1] = bl1;
        }
        __syncthreads();
        if (ks < 3) {     // issue next-stage loads early (hide under MFMA)
            int K0 = (ks + 1) * 64;
            const float* ap = &A[(size_t)(R0 + sr) * DIM + K0 + skq];
            areg0 = *(const float4*)&ap[0];  areg1 = *(const float4*)&ap[4];
            areg2 = *(const float4*)&ap[8];  areg3 = *(const float4*)&ap[12];
            size_t bb = (size_t)(C0 + sr) * DIM + K0 + skq;
            bh0 = *(const uint4*)&BThi[bb]; bh1 = *(const uint4*)&BThi[bb + 8];
            bl0 = *(const uint4*)&BTlo[bb]; bl1 = *(const uint4*)&BTlo[bb + 8];
        }
#pragma unroll
        for (int kk = 0; kk < 2; ++kk) {
            int kb = kk * 32 + l4 * 8;
            short8 ah[2], al[2], bh[2], bl[2];
#pragma unroll
            for (int h = 0; h < 2; ++h) {
                int arow = wr * 32 + h * 16 + l15;
                int aidx = (arow * 64 + kb) ^ ((arow & 7) << 3);
                ah[h] = *(const short8*)&Ah[aidx];
                al[h] = *(const short8*)&Al[aidx];
                int bcol = wc * 32 + h * 16 + l15;
                int bidx = (bcol * 64 + kb) ^ ((bcol & 7) << 3);
                bh[h] = *(const short8*)&Bh[bidx];
                bl[h] = *(const short8*)&Bl[bidx];
            }
#pragma unroll
            for (int i = 0; i < 2; ++i)
#pragma unroll
                for (int j = 0; j < 2; ++j) {
                    acc[i][j] = __builtin_amdgcn_mfma_f32_16x16x32_bf16(ah[i], bh[j], acc[i][j], 0, 0, 0);
                    acc[i][j] = __builtin_amdgcn_mfma_f32_16x16x32_bf16(ah[i], bl[j], acc[i][j], 0, 0, 0);
                    acc[i][j] = __builtin_amdgcn_mfma_f32_16x16x32_bf16(al[i], bh[j], acc[i][j], 0, 0, 0);
                    acc[i][j] = __builtin_amdgcn_mfma_f32_16x16x32_bf16(al[i], bl[j], acc[i][j], 0, 0, 0);
                }
        }
        __syncthreads();
    }

    // epilogue: exp2(C2*x), bounce-transpose, coalesced global writes
#pragma unroll
    for (int i = 0; i < 2; ++i)
#pragma unroll
        for (int j = 0; j < 2; ++j) {
            float ev[4];
#pragma unroll
            for (int v = 0; v < 4; ++v) ev[v] = __builtin_amdgcn_exp2f(C2 * acc[i][j][v]);
            int row = wr * 32 + i * 16 + l4 * 4;   // +v consecutive
            int col = wc * 32 + j * 16 + l15;
            if (isK) {
#pragma unroll
                for (int v = 0; v < 4; ++v) T[row + v][col] = ev[v];
            } else {
                *(float4*)&T[col][row] = make_float4(ev[0], ev[1], ev[2], ev[3]);
            }
        }
    __syncthreads();
    {
        int r = tid >> 2, q = tid & 3;
        float* dst = isK ? &EK[(size_t)b * DIM * DIM + (size_t)(R0 + r) * DIM + C0 + q * 16]
                         : &EQ[(size_t)b * DIM * DIM + (size_t)(C0 + r) * DIM + R0 + q * 16];
#pragma unroll
        for (int i = 0; i < 4; ++i)
            *(float4*)&dst[i * 4] = *(const float4*)&T[r][q * 16 + i * 4];
    }
}

// ---------------- fused scores + softmax(axis=n) -> attnN hi/lo bf16 [n][m] ----------------
#define CH 16
__global__ __launch_bounds__(512, 2) void scores_softmax_kernel(
    const float* __restrict__ EQ, const float* __restrict__ EK,
    const float* __restrict__ Wv,
    ushort_t* __restrict__ ANh, ushort_t* __restrict__ ANl)
{
    int b  = blockIdx.y;
    int M0 = blockIdx.x * 8;
    const float* Qb = EQ + b * DIM * DIM;   // [h][n]
    const float* Kb = EK + b * DIM * DIM;   // [m][h]

    __shared__ __align__(16) float Qs[2][CH * 256];    // 32 KB dbuf h-chunks
    __shared__ __align__(16) float Eks[8][DIM];        // 8 KB [m][h]
    __shared__ __align__(16) float Ws[DIM];            // 1 KB
    __shared__ __align__(16) float part[3][2][64][16]; // 24 KB h-split exchange

    int tid  = threadIdx.x;
    int w = tid >> 6, lane = tid & 63;
    int mg = w & 1, hs = w >> 1;      // m-group 0..1, h-split 0..3
    int n0 = lane * 4;

    {   // stage Eks: 8 m-rows x 256 h
        int m = tid >> 6, h4 = (tid & 63) * 4;
        *(float4*)&Eks[m][h4] = *(const float4*)&Kb[(M0 + m) * DIM + h4];
    }
    if (tid < 64) *(float4*)&Ws[tid * 4] = *(const float4*)&Wv[tid * 4];
    *(float4*)&Qs[0][tid * 4]        = *(const float4*)&Qb[tid * 4];
    *(float4*)&Qs[0][2048 + tid * 4] = *(const float4*)&Qb[2048 + tid * 4];
    __syncthreads();

    float wsum;
    {
        float4 w4 = *(const float4*)&Ws[lane * 4];
        wsum = w4.x + w4.y + w4.z + w4.w;
#pragma unroll
        for (int o = 32; o; o >>= 1) wsum += __shfl_xor(wsum, o);
    }

    float acc[4][4] = {};   // [m-row][n]
    int buf = 0;

    for (int c = 0; c < 16; ++c) {
        float4 nx0, nx1;
        if (c < 15) {
            const float* s = Qb + (c + 1) * (CH * 256);
            nx0 = *(const float4*)&s[tid * 4];
            nx1 = *(const float4*)&s[2048 + tid * 4];
        }
        float4 wv4 = *(const float4*)&Ws[c * CH + hs * 4];
        float wva[4] = {wv4.x, wv4.y, wv4.z, wv4.w};
        float eka[4][4];
#pragma unroll
        for (int i = 0; i < 4; ++i) {
            float4 e4 = *(const float4*)&Eks[mg * 4 + i][c * CH + hs * 4];
            eka[i][0] = e4.x; eka[i][1] = e4.y; eka[i][2] = e4.z; eka[i][3] = e4.w;
        }
        const float* Qc = &Qs[buf][(hs * 4) * 256];
#pragma unroll
        for (int hh = 0; hh < 2; ++hh) {
            float4 q0 = *(const float4*)&Qc[(hh * 2) * 256 + n0];
            float4 q1 = *(const float4*)&Qc[(hh * 2 + 1) * 256 + n0];
            float q0a[4] = {q0.x, q0.y, q0.z, q0.w};
            float q1a[4] = {q1.x, q1.y, q1.z, q1.w};
            float w0 = wva[hh * 2], w1 = wva[hh * 2 + 1];
#pragma unroll
            for (int i = 0; i < 4; ++i) {
                float e0 = eka[i][hh * 2], e1 = eka[i][hh * 2 + 1];
#pragma unroll
                for (int j = 0; j < 4; ++j) {
                    float d0 = fmaf(q0a[j], e0, 1.0f);
                    float d1 = fmaf(q1a[j], e1, 1.0f);
                    float num = fmaf(w0, d1, w1 * d0);
                    acc[i][j] = fmaf(num, __builtin_amdgcn_rcpf(d0 * d1), acc[i][j]);
                }
            }
        }
        if (c < 15) {
            *(float4*)&Qs[buf ^ 1][tid * 4] = nx0;
            *(float4*)&Qs[buf ^ 1][2048 + tid * 4] = nx1;
        }
        __syncthreads();
        buf ^= 1;
    }

    if (hs) {
#pragma unroll
        for (int i = 0; i < 4; ++i) {
            float4 v = make_float4(acc[i][0], acc[i][1], acc[i][2], acc[i][3]);
            *(float4*)&part[hs - 1][mg][lane][i * 4] = v;
        }
    }
    __syncthreads();
    if (hs == 0) {
#pragma unroll
        for (int p = 0; p < 3; ++p)
#pragma unroll
            for (int i = 0; i < 4; ++i) {
                float4 v = *(const float4*)&part[p][mg][lane][i * 4];
                acc[i][0] += v.x; acc[i][1] += v.y; acc[i][2] += v.z; acc[i][3] += v.w;
            }
        float e[4][4], t[4], ri[4];
#pragma unroll
        for (int i = 0; i < 4; ++i) {
            t[i] = 0.0f;
#pragma unroll
            for (int j = 0; j < 4; ++j) {
                e[i][j] = __builtin_amdgcn_exp2f((wsum - 2.0f * acc[i][j]) * LOG2E);
                t[i] += e[i][j];
            }
        }
#pragma unroll
        for (int o = 32; o; o >>= 1)
#pragma unroll
            for (int i = 0; i < 4; ++i) t[i] += __shfl_xor(t[i], o);
#pragma unroll
        for (int i = 0; i < 4; ++i) ri[i] = __builtin_amdgcn_rcpf(t[i]);
        // emit attn bf16 hi/lo in [n][m] layout (av's A-operand)
#pragma unroll
        for (int j = 0; j < 4; ++j) {
            float a0 = e[0][j] * ri[0], a1 = e[1][j] * ri[1];
            float a2 = e[2][j] * ri[2], a3 = e[3][j] * ri[3];
            size_t base = ((size_t)b * DIM + n0 + j) * DIM + M0 + mg * 4;
            *(uint2*)&ANh[base] = make_uint2(hi2(a0, a1), hi2(a2, a3));
            *(uint2*)&ANl[base] = make_uint2(hi2(trunc_res(a0), trunc_res(a1)),
                                             hi2(trunc_res(a2), trunc_res(a3)));
        }
    }
}

// ---------------- av (MFMA): out[b][n][d] = sum_m attnN[n][m] * V[m][d] ----------------
__global__ __launch_bounds__(256) void av_mfma(
    const ushort_t* __restrict__ ANh, const ushort_t* __restrict__ ANl,
    const ushort_t* __restrict__ VTh, const ushort_t* __restrict__ VTl,
    float* __restrict__ out)
{
    __shared__ __align__(16) ushort_t Ah[64 * 64], Al[64 * 64], Bh[64 * 64], Bl[64 * 64];
    __shared__ __align__(16) float T[64][68];

    int b = blockIdx.y;
    int x = blockIdx.x;
    int R0 = (x >> 2) * 64, C0 = (x & 3) * 64;   // n-tile, d-tile
    const ushort_t* Abh = ANh + (size_t)b * DIM * DIM;
    const ushort_t* Abl = ANl + (size_t)b * DIM * DIM;
    const ushort_t* Bbh = VTh + (size_t)b * DIM * DIM;
    const ushort_t* Bbl = VTl + (size_t)b * DIM * DIM;

    int tid = threadIdx.x;
    int w = tid >> 6, lane = tid & 63;
    int wr = w >> 1, wc = w & 1;
    int l15 = lane & 15, l4 = lane >> 4;
    int sr = tid >> 2, skq = (tid & 3) * 16;

    f32x4 acc[2][2] = {};
    uint4 ah0, ah1, al0, al1, bh0, bh1, bl0, bl1;
    {
        size_t aa = (size_t)(R0 + sr) * DIM + skq;
        size_t bb = (size_t)(C0 + sr) * DIM + skq;
        ah0 = *(const uint4*)&Abh[aa]; ah1 = *(const uint4*)&Abh[aa + 8];
        al0 = *(const uint4*)&Abl[aa]; al1 = *(const uint4*)&Abl[aa + 8];
        bh0 = *(const uint4*)&Bbh[bb]; bh1 = *(const uint4*)&Bbh[bb + 8];
        bl0 = *(const uint4*)&Bbl[bb]; bl1 = *(const uint4*)&Bbl[bb + 8];
    }

    for (int ks = 0; ks < 4; ++ks) {
        {
            int i0 = (sr * 64 + skq)     ^ ((sr & 7) << 3);
            int i1 = (sr * 64 + skq + 8) ^ ((sr & 7) << 3);
            *(uint4*)&Ah[i0] = ah0; *(uint4*)&Ah[i1] = ah1;
            *(uint4*)&Al[i0] = al0; *(uint4*)&Al[i1] = al1;
            *(uint4*)&Bh[i0] = bh0; *(uint4*)&Bh[i1] = bh1;
            *(uint4*)&Bl[i0] = bl0; *(uint4*)&Bl[i1] = bl1;
        }
        __syncthreads();
        if (ks < 3) {
            int K0 = (ks + 1) * 64;
            size_t aa = (size_t)(R0 + sr) * DIM + K0 + skq;
            size_t bb = (size_t)(C0 + sr) * DIM + K0 + skq;
            ah0 = *(const uint4*)&Abh[aa]; ah1 = *(const uint4*)&Abh[aa + 8];
            al0 = *(const uint4*)&Abl[aa]; al1 = *(const uint4*)&Abl[aa + 8];
            bh0 = *(const uint4*)&Bbh[bb]; bh1 = *(const uint4*)&Bbh[bb + 8];
            bl0 = *(const uint4*)&Bbl[bb]; bl1 = *(const uint4*)&Bbl[bb + 8];
        }
#pragma unroll
        for (int kk = 0; kk < 2; ++kk) {
            int kb = kk * 32 + l4 * 8;
            short8 ah[2], al[2], bh[2], bl[2];
#pragma unroll
            for (int h = 0; h < 2; ++h) {
                int arow = wr * 32 + h * 16 + l15;
                int aidx = (arow * 64 + kb) ^ ((arow & 7) << 3);
                ah[h] = *(const short8*)&Ah[aidx];
                al[h] = *(const short8*)&Al[aidx];
                int bcol = wc * 32 + h * 16 + l15;
                int bidx = (bcol * 64 + kb) ^ ((bcol & 7) << 3);
                bh[h] = *(const short8*)&Bh[bidx];
                bl[h] = *(const short8*)&Bl[bidx];
            }
#pragma unroll
            for (int i = 0; i < 2; ++i)
#pragma unroll
                for (int j = 0; j < 2; ++j) {
                    acc[i][j] = __builtin_amdgcn_mfma_f32_16x16x32_bf16(ah[i], bh[j], acc[i][j], 0, 0, 0);
                    acc[i][j] = __builtin_amdgcn_mfma_f32_16x16x32_bf16(ah[i], bl[j], acc[i][j], 0, 0, 0);
                    acc[i][j] = __builtin_amdgcn_mfma_f32_16x16x32_bf16(al[i], bh[j], acc[i][j], 0, 0, 0);
                    acc[i][j] = __builtin_amdgcn_mfma_f32_16x16x32_bf16(al[i], bl[j], acc[i][j], 0, 0, 0);
                }
        }
        __syncthreads();
    }

    // epilogue: bounce to LDS row-major, coalesced fp32 writes
#pragma unroll
    for (int i = 0; i < 2; ++i)
#pragma unroll
        for (int j = 0; j < 2; ++j) {
            int row = wr * 32 + i * 16 + l4 * 4;
            int col = wc * 32 + j * 16 + l15;
#pragma unroll
            for (int v = 0; v < 4; ++v) T[row + v][col] = acc[i][j][v];
        }
    __syncthreads();
    {
        int r = tid >> 2, q = tid & 3;
        float* dst = &out[((size_t)b * DIM + R0 + r) * DIM + C0 + q * 16];
#pragma unroll
        for (int i = 0; i < 4; ++i)
            *(float4*)&dst[i * 4] = *(const float4*)&T[r][q * 16 + i * 4];
    }
}

extern "C" void kernel_launch(void* const* d_in, const int* in_sizes, int n_in,
                              void* d_out, int out_size, void* d_ws, size_t ws_size,
                              hipStream_t stream)
{
    const float* query = (const float*)d_in[0];
    const float* key   = (const float*)d_in[1];
    const float* value = (const float*)d_in[2];
    const float* Wq    = (const float*)d_in[3];
    const float* Wk    = (const float*)d_in[4];
    const float* Wv    = (const float*)d_in[5];
    float* out = (float*)d_out;

    float* EQ = (float*)d_ws;                     // [8][h][n] fp32
    float* EK = EQ + N_B * DIM * DIM;             // [8][m][h] fp32
    ushort_t* us = (ushort_t*)(EK + N_B * DIM * DIM);
    ushort_t* WqT_hi = us; us += DIM * DIM;
    ushort_t* WqT_lo = us; us += DIM * DIM;
    ushort_t* WkT_hi = us; us += DIM * DIM;
    ushort_t* WkT_lo = us; us += DIM * DIM;
    ushort_t* VT_hi  = us; us += N_B * DIM * DIM;
    ushort_t* VT_lo  = us; us += N_B * DIM * DIM;
    ushort_t* ANh    = us; us += N_B * DIM * DIM;
    ushort_t* ANl    = us; us += N_B * DIM * DIM;

    prep_kernel<<<160, 256, 0, stream>>>(Wq, Wk, value,
                                         WqT_hi, WqT_lo, WkT_hi, WkT_lo, VT_hi, VT_lo);
    proj_mfma<<<dim3(16, 16), 256, 0, stream>>>(query, key,
                                                WqT_hi, WqT_lo, WkT_hi, WkT_lo, EQ, EK);
    scores_softmax_kernel<<<dim3(32, 8), 512, 0, stream>>>(EQ, EK, Wv, ANh, ANl);
    av_mfma<<<dim3(16, 8), 256, 0, stream>>>(ANh, ANl, VT_hi, VT_lo, out);
}